// Round 1
// baseline (247.577 us; speedup 1.0000x reference)
//
#include <hip/hip_runtime.h>

#define NN 4096
#define ROW_BLOCKS 256
#define ROWS_PER_BLOCK (NN / ROW_BLOCKS)  // 16

// Phase 1: partial column sums of yin @ (w + alpha*hebb).
// Grid: (NN/1024 = 4 column blocks) x ROW_BLOCKS. Block: 256 threads,
// each thread owns 4 consecutive columns (float4), iterates its row slice.
__global__ __launch_bounds__(256) void matvec_partial_kernel(
    const float* __restrict__ yin,
    const float* __restrict__ w,
    const float* __restrict__ alpha,
    const float* __restrict__ hebb,
    float* __restrict__ t_acc)
{
    const int col = blockIdx.x * 1024 + threadIdx.x * 4;
    const int r0  = blockIdx.y * ROWS_PER_BLOCK;

    float4 acc = make_float4(0.f, 0.f, 0.f, 0.f);
    #pragma unroll
    for (int ii = 0; ii < ROWS_PER_BLOCK; ++ii) {
        const int i = r0 + ii;
        const float yv = yin[i];                      // block-uniform -> s_load
        const size_t off = (size_t)i * NN + col;
        const float4 wv = *reinterpret_cast<const float4*>(w + off);
        const float4 av = *reinterpret_cast<const float4*>(alpha + off);
        const float4 hv = *reinterpret_cast<const float4*>(hebb + off);
        acc.x += yv * (wv.x + av.x * hv.x);
        acc.y += yv * (wv.y + av.y * hv.y);
        acc.z += yv * (wv.z + av.z * hv.z);
        acc.w += yv * (wv.w + av.w * hv.w);
    }
    atomicAdd(&t_acc[col + 0], acc.x);
    atomicAdd(&t_acc[col + 1], acc.y);
    atomicAdd(&t_acc[col + 2], acc.z);
    atomicAdd(&t_acc[col + 3], acc.w);
}

// Phase 2: yout[j] = tanh(t[j] + input[j])
__global__ __launch_bounds__(256) void yout_kernel(
    const float* __restrict__ t_acc,
    const float* __restrict__ input,
    float* __restrict__ yout)
{
    const int j = blockIdx.x * 256 + threadIdx.x;
    yout[j] = tanhf(t_acc[j] + input[j]);
}

// Phase 3: hebb'[i][j] = (1-eta)*hebb[i][j] + (eta*yin[i])*yout[j]
__global__ __launch_bounds__(256) void hebb_update_kernel(
    const float* __restrict__ hebb,
    const float* __restrict__ yin,
    const float* __restrict__ yout,
    const float* __restrict__ eta_p,
    float* __restrict__ hebb_out)
{
    const float eta = eta_p[0];
    const float om  = 1.0f - eta;
    const int total4 = NN * NN / 4;
    const int stride = gridDim.x * blockDim.x;
    for (int g = blockIdx.x * blockDim.x + threadIdx.x; g < total4; g += stride) {
        const int row = g >> 10;          // NN/4 = 1024 float4 per row
        const float ye = eta * yin[row];
        const float4 h  = reinterpret_cast<const float4*>(hebb)[g];
        const float4 yo = reinterpret_cast<const float4*>(yout)[g & 1023];
        float4 r;
        r.x = om * h.x + ye * yo.x;
        r.y = om * h.y + ye * yo.y;
        r.z = om * h.z + ye * yo.z;
        r.w = om * h.w + ye * yo.w;
        reinterpret_cast<float4*>(hebb_out)[g] = r;
    }
}

extern "C" void kernel_launch(void* const* d_in, const int* in_sizes, int n_in,
                              void* d_out, int out_size, void* d_ws, size_t ws_size,
                              hipStream_t stream) {
    const float* input = (const float*)d_in[0];
    const float* yin   = (const float*)d_in[1];
    const float* hebb  = (const float*)d_in[2];
    const float* w     = (const float*)d_in[3];
    const float* alpha = (const float*)d_in[4];
    const float* eta   = (const float*)d_in[5];

    float* out      = (float*)d_out;
    float* yout     = out;        // first NN elements
    float* hebb_out = out + NN;   // next NN*NN elements (16 KiB offset, 16B aligned)
    float* t_acc    = (float*)d_ws;

    // d_ws is re-poisoned to 0xAA before every launch -> zero the accumulator.
    hipMemsetAsync(t_acc, 0, NN * sizeof(float), stream);

    dim3 g1(NN / 1024, ROW_BLOCKS);
    matvec_partial_kernel<<<g1, 256, 0, stream>>>(yin, w, alpha, hebb, t_acc);

    yout_kernel<<<NN / 256, 256, 0, stream>>>(t_acc, input, yout);

    hebb_update_kernel<<<2048, 256, 0, stream>>>(hebb, yin, yout, eta, hebb_out);
}

// Round 2
// 244.885 us; speedup vs baseline: 1.0110x; 1.0110x over previous
//
#include <hip/hip_runtime.h>

#define NN 4096
#define CB 4            // column blocks (x-dim)
#define RPB 16          // rows per block
#define RBATCH 4        // rows per load batch (12 float4 loads in flight)
#define YB (NN / RPB)   // 256 row-blocks (y-dim)

// ---------------- Phase 1: partial column sums of yin @ (w + alpha*hebb) ----
// Grid (CB, YB), block 256. Each thread owns 4 consecutive columns and
// accumulates over this block's 16 rows, batching loads for MLP.
// PARTIAL=1: write per-rowblock partials to part[by*NN + col].
// PARTIAL=0: atomicAdd into t_acc[col] (fallback if d_ws too small).
template <int PARTIAL>
__global__ __launch_bounds__(256) void matvec_partial_kernel(
    const float* __restrict__ yin,
    const float* __restrict__ w,
    const float* __restrict__ alpha,
    const float* __restrict__ hebb,
    float* __restrict__ part)
{
    const int col = blockIdx.x * 1024 + threadIdx.x * 4;
    const int r0  = blockIdx.y * RPB;

    float4 acc = make_float4(0.f, 0.f, 0.f, 0.f);
    #pragma unroll
    for (int b = 0; b < RPB / RBATCH; ++b) {
        float4 wv[RBATCH], av[RBATCH], hv[RBATCH];
        float  yv[RBATCH];
        #pragma unroll
        for (int k = 0; k < RBATCH; ++k) {
            const int i = r0 + b * RBATCH + k;
            const size_t off = (size_t)i * NN + col;
            wv[k] = *reinterpret_cast<const float4*>(w + off);
            av[k] = *reinterpret_cast<const float4*>(alpha + off);
            hv[k] = *reinterpret_cast<const float4*>(hebb + off);
            yv[k] = yin[i];
        }
        #pragma unroll
        for (int k = 0; k < RBATCH; ++k) {
            acc.x += yv[k] * (wv[k].x + av[k].x * hv[k].x);
            acc.y += yv[k] * (wv[k].y + av[k].y * hv[k].y);
            acc.z += yv[k] * (wv[k].z + av[k].z * hv[k].z);
            acc.w += yv[k] * (wv[k].w + av[k].w * hv[k].w);
        }
    }

    if (PARTIAL) {
        *reinterpret_cast<float4*>(part + (size_t)blockIdx.y * NN + col) = acc;
    } else {
        atomicAdd(&part[col + 0], acc.x);
        atomicAdd(&part[col + 1], acc.y);
        atomicAdd(&part[col + 2], acc.z);
        atomicAdd(&part[col + 3], acc.w);
    }
}

// ---------------- Phase 2a (partial path): reduce YB partials -> yout -------
// Grid 64 blocks x 256. Block handles 64 columns; 4 k-slices of 64 each,
// LDS-reduced. All loads coalesced (lanes span consecutive columns).
__global__ __launch_bounds__(256) void reduce_yout_kernel(
    const float* __restrict__ part,
    const float* __restrict__ input,
    float* __restrict__ yout)
{
    const int tid   = threadIdx.x;
    const int j     = blockIdx.x * 64 + (tid & 63);
    const int slice = tid >> 6;           // 0..3, each sums 64 row-blocks

    float s = 0.f;
    #pragma unroll 8
    for (int kk = 0; kk < YB / 4; ++kk)
        s += part[(size_t)(slice * (YB / 4) + kk) * NN + j];

    __shared__ float sm[256];
    sm[tid] = s;
    __syncthreads();
    if (tid < 64) {
        float tot = sm[tid] + sm[tid + 64] + sm[tid + 128] + sm[tid + 192];
        yout[j] = tanhf(tot + input[j]);
    }
}

// ---------------- Phase 2b (atomic fallback): yout = tanh(t + input) --------
__global__ __launch_bounds__(256) void yout_kernel(
    const float* __restrict__ t_acc,
    const float* __restrict__ input,
    float* __restrict__ yout)
{
    const int j = blockIdx.x * 256 + threadIdx.x;
    yout[j] = tanhf(t_acc[j] + input[j]);
}

// ---------------- Phase 3: hebb' = (1-eta)*hebb + eta*outer(yin,yout) -------
// 2048 blocks x 256 threads x 8 float4 = exactly NN*NN floats.
// Loads batched (8 hebb float4 + 8 yin scalars in flight), then compute+store.
__global__ __launch_bounds__(256) void hebb_update_kernel(
    const float* __restrict__ hebb,
    const float* __restrict__ yin,
    const float* __restrict__ yout,
    const float* __restrict__ eta_p,
    float* __restrict__ hebb_out)
{
    const float eta = eta_p[0];
    const float om  = 1.0f - eta;
    const int tid   = blockIdx.x * 256 + threadIdx.x;   // 0..524287
    const int NT    = 2048 * 256;                       // stride (float4 units)

    // stride is a multiple of 1024 (float4 per row) -> column index constant
    const float4 yo = reinterpret_cast<const float4*>(yout)[tid & 1023];

    float4 hv[8];
    float  ye[8];
    #pragma unroll
    for (int it = 0; it < 8; ++it) {
        const int g = tid + it * NT;
        hv[it] = reinterpret_cast<const float4*>(hebb)[g];
        ye[it] = eta * yin[g >> 10];
    }
    #pragma unroll
    for (int it = 0; it < 8; ++it) {
        const int g = tid + it * NT;
        float4 r;
        r.x = om * hv[it].x + ye[it] * yo.x;
        r.y = om * hv[it].y + ye[it] * yo.y;
        r.z = om * hv[it].z + ye[it] * yo.z;
        r.w = om * hv[it].w + ye[it] * yo.w;
        reinterpret_cast<float4*>(hebb_out)[g] = r;
    }
}

extern "C" void kernel_launch(void* const* d_in, const int* in_sizes, int n_in,
                              void* d_out, int out_size, void* d_ws, size_t ws_size,
                              hipStream_t stream) {
    const float* input = (const float*)d_in[0];
    const float* yin   = (const float*)d_in[1];
    const float* hebb  = (const float*)d_in[2];
    const float* w     = (const float*)d_in[3];
    const float* alpha = (const float*)d_in[4];
    const float* eta   = (const float*)d_in[5];

    float* out      = (float*)d_out;
    float* yout     = out;        // first NN elements
    float* hebb_out = out + NN;   // next NN*NN elements (16 KiB offset, aligned)

    const size_t part_bytes = (size_t)YB * NN * sizeof(float);  // 4 MiB
    dim3 g1(CB, YB);

    if (ws_size >= part_bytes) {
        float* part = (float*)d_ws;   // fully overwritten, no memset needed
        matvec_partial_kernel<1><<<g1, 256, 0, stream>>>(yin, w, alpha, hebb, part);
        reduce_yout_kernel<<<NN / 64, 256, 0, stream>>>(part, input, yout);
    } else {
        float* t_acc = (float*)d_ws;  // 16 KiB accumulator, must be zeroed
        hipMemsetAsync(t_acc, 0, NN * sizeof(float), stream);
        matvec_partial_kernel<0><<<g1, 256, 0, stream>>>(yin, w, alpha, hebb, t_acc);
        yout_kernel<<<NN / 256, 256, 0, stream>>>(t_acc, input, yout);
    }

    hebb_update_kernel<<<2048, 256, 0, stream>>>(hebb, yin, yout, eta, hebb_out);
}